// Round 11
// baseline (143.076 us; speedup 1.0000x reference)
//
#include <hip/hip_runtime.h>
#include <math.h>

#define HIDDEN 128
#define HEADS 8
#define HDIM 16
#define NSEQ 512
#define NBATCH 4
#define SROW 9          // sS/sB row stride
#define NEGINF (-1e30f)

typedef _Float16 half8 __attribute__((ext_vector_type(8)));
typedef float f32x4 __attribute__((ext_vector_type(4)));

// ---------------- Kernel 1: fused Q/K/V projection ----------------
__global__ __launch_bounds__(128) void qkv_proj(
    const float* __restrict__ node,
    const float* __restrict__ Wq, const float* __restrict__ bq,
    const float* __restrict__ Wk, const float* __restrict__ bk,
    const float* __restrict__ Wv, const float* __restrict__ bv,
    float* __restrict__ Q, float* __restrict__ K, float* __restrict__ V)
{
    const int ROWS = 8;
    __shared__ float sX[ROWS][HIDDEN];
    const int row0 = blockIdx.x * ROWS;
    const int tid = threadIdx.x;

    const float4* src = (const float4*)(node + row0 * HIDDEN);
    float4* dst = (float4*)(&sX[0][0]);
    #pragma unroll
    for (int i = 0; i < ROWS * HIDDEN / 4 / 128; i++)
        dst[tid + i * 128] = src[tid + i * 128];
    __syncthreads();

    float accQ[ROWS], accK[ROWS], accV[ROWS];
    #pragma unroll
    for (int r = 0; r < ROWS; r++) { accQ[r] = 0.f; accK[r] = 0.f; accV[r] = 0.f; }
    const int c = tid;
    #pragma unroll 8
    for (int d = 0; d < HIDDEN; d++) {
        const float wq = Wq[d * HIDDEN + c];
        const float wk = Wk[d * HIDDEN + c];
        const float wv = Wv[d * HIDDEN + c];
        #pragma unroll
        for (int r = 0; r < ROWS; r++) {
            const float x = sX[r][d];
            accQ[r] = fmaf(x, wq, accQ[r]);
            accK[r] = fmaf(x, wk, accK[r]);
            accV[r] = fmaf(x, wv, accV[r]);
        }
    }
    const float bqv = bq[c], bkv = bk[c], bvv = bv[c];
    #pragma unroll
    for (int r = 0; r < ROWS; r++) {
        const int off = (row0 + r) * HIDDEN + c;
        Q[off] = accQ[r] + bqv;
        K[off] = accK[r] + bkv;
        V[off] = accV[r] + bvv;
    }
}

// ---------------- Kernel 2: fused attention with index compaction ----------
// Prologue: deterministic ballot/prefix compaction of unmasked k -> sIdx
// (k-sorted). All phases then run over compacted positions only:
//   stream: ntiles = ceil(cnt/16) MFMA bias tiles (all lanes live)
//   QK^T:   only unmasked k (masked entries never read downstream)
//   softmax/PV: loops over cnt positions.
__global__ __launch_bounds__(256, 3) void attn_fused(
    const float* __restrict__ ef,     // [B][N][N][HIDDEN]
    const int*   __restrict__ mask,   // [B][N][N]
    const float* __restrict__ We,     // [HIDDEN][HEADS]
    const float* __restrict__ be,     // [HEADS]
    const float* __restrict__ Q, const float* __restrict__ K,
    const float* __restrict__ V,
    float* __restrict__ attn)         // [B*N][HIDDEN]
{
    __shared__ float sS[NSEQ * SROW];   // scores (unmasked k only) -> weights
    __shared__ float sB[NSEQ * SROW];   // edge bias; reused as sPd after softmax
    __shared__ int   sIdx[NSEQ];
    __shared__ int   sWcnt[8];

    const int bq = blockIdx.x;
    const int b  = bq >> 9;
    const int tid = threadIdx.x;
    const int wvid = tid >> 6;
    const int lane = tid & 63;
    const int row16 = lane & 15;        // A row within tile / C col (head)
    const int g = lane >> 4;            // k-slice group 0..3
    const int h = row16;                // head for sB writeback (h<8 valid)

    const float4* efb4 = (const float4*)(ef + (size_t)bq * NSEQ * HIDDEN);
    const int* mbase = mask + (size_t)bq * NSEQ;

    // ---- compaction: chunks of 64; wave w owns chunks 2w, 2w+1 ----
    const int k_c0 = wvid * 128 + lane;
    const int k_c1 = k_c0 + 64;
    const int m_c0 = mbase[k_c0];
    const int m_c1 = mbase[k_c1];
    const unsigned long long bal0 = __ballot(m_c0 != 0);
    const unsigned long long bal1 = __ballot(m_c1 != 0);
    if (lane == 0) {
        sWcnt[wvid * 2 + 0] = __popcll(bal0);
        sWcnt[wvid * 2 + 1] = __popcll(bal1);
    }
    __syncthreads();
    {
        int c0 = sWcnt[0], c1 = sWcnt[1], c2 = sWcnt[2], c3 = sWcnt[3];
        int c4 = sWcnt[4], c5 = sWcnt[5], c6 = sWcnt[6], c7 = sWcnt[7];
        int pre[8];
        pre[0] = 0;       pre[1] = c0;
        pre[2] = pre[1] + c1; pre[3] = pre[2] + c2;
        pre[4] = pre[3] + c3; pre[5] = pre[4] + c4;
        pre[6] = pre[5] + c5; pre[7] = pre[6] + c6;
        const unsigned long long lt = (lane == 0) ? 0ull
            : (~0ull >> (64 - lane));
        if (m_c0) sIdx[pre[wvid * 2 + 0] + __popcll(bal0 & lt)] = k_c0;
        if (m_c1) sIdx[pre[wvid * 2 + 1] + __popcll(bal1 & lt)] = k_c1;
    }
    __syncthreads();
    const int cnt = sWcnt[0] + sWcnt[1] + sWcnt[2] + sWcnt[3]
                  + sWcnt[4] + sWcnt[5] + sWcnt[6] + sWcnt[7];
    const int ntiles = (cnt + 15) >> 4;

    // ---- B fragments (We): lane holds We[32*ks + 8g + j][h] ----
    half8 Bf0, Bf1, Bf2, Bf3;
    #pragma unroll
    for (int j = 0; j < 8; j++) {
        const int dbase = 8 * g + j;
        Bf0[j] = (_Float16)(h < 8 ? We[(dbase +  0) * 8 + h] : 0.f);
        Bf1[j] = (_Float16)(h < 8 ? We[(dbase + 32) * 8 + h] : 0.f);
        Bf2[j] = (_Float16)(h < 8 ? We[(dbase + 64) * 8 + h] : 0.f);
        Bf3[j] = (_Float16)(h < 8 ? We[(dbase + 96) * 8 + h] : 0.f);
    }

    const float4 z = make_float4(0.f, 0.f, 0.f, 0.f);
    auto LOADC = [&](int t, float4& a0, float4& a1, float4& a2, float4& a3,
                     float4& a4, float4& a5, float4& a6, float4& a7) {
        a0 = z; a1 = z; a2 = z; a3 = z; a4 = z; a5 = z; a6 = z; a7 = z;
        const int pidx = 16 * t + row16;
        const int ok = pidx < cnt;
        const int k = ok ? sIdx[pidx] : 0;
        const float4* p = efb4 + (size_t)k * 32 + 2 * g;
        if (ok) {
            a0 = p[0];  a1 = p[1];
            a2 = p[8];  a3 = p[9];
            a4 = p[16]; a5 = p[17];
            a6 = p[24]; a7 = p[25];
        }
    };
    auto COMPC = [&](int t, const float4& a0, const float4& a1, const float4& a2,
                     const float4& a3, const float4& a4, const float4& a5,
                     const float4& a6, const float4& a7) {
        f32x4 acc = {0.f, 0.f, 0.f, 0.f};
        half8 A;
        A[0]=(_Float16)a0.x; A[1]=(_Float16)a0.y; A[2]=(_Float16)a0.z; A[3]=(_Float16)a0.w;
        A[4]=(_Float16)a1.x; A[5]=(_Float16)a1.y; A[6]=(_Float16)a1.z; A[7]=(_Float16)a1.w;
        acc = __builtin_amdgcn_mfma_f32_16x16x32_f16(A, Bf0, acc, 0, 0, 0);
        A[0]=(_Float16)a2.x; A[1]=(_Float16)a2.y; A[2]=(_Float16)a2.z; A[3]=(_Float16)a2.w;
        A[4]=(_Float16)a3.x; A[5]=(_Float16)a3.y; A[6]=(_Float16)a3.z; A[7]=(_Float16)a3.w;
        acc = __builtin_amdgcn_mfma_f32_16x16x32_f16(A, Bf1, acc, 0, 0, 0);
        A[0]=(_Float16)a4.x; A[1]=(_Float16)a4.y; A[2]=(_Float16)a4.z; A[3]=(_Float16)a4.w;
        A[4]=(_Float16)a5.x; A[5]=(_Float16)a5.y; A[6]=(_Float16)a5.z; A[7]=(_Float16)a5.w;
        acc = __builtin_amdgcn_mfma_f32_16x16x32_f16(A, Bf2, acc, 0, 0, 0);
        A[0]=(_Float16)a6.x; A[1]=(_Float16)a6.y; A[2]=(_Float16)a6.z; A[3]=(_Float16)a6.w;
        A[4]=(_Float16)a7.x; A[5]=(_Float16)a7.y; A[6]=(_Float16)a7.z; A[7]=(_Float16)a7.w;
        acc = __builtin_amdgcn_mfma_f32_16x16x32_f16(A, Bf3, acc, 0, 0, 0);
        if (h < 8) {    // rows = compact positions 16t+4g+0..3, scatter via sIdx
            const int pb0 = 16 * t + 4 * g;
            const int k0 = (pb0 + 0 < cnt) ? sIdx[pb0 + 0] : -1;
            const int k1 = (pb0 + 1 < cnt) ? sIdx[pb0 + 1] : -1;
            const int k2 = (pb0 + 2 < cnt) ? sIdx[pb0 + 2] : -1;
            const int k3 = (pb0 + 3 < cnt) ? sIdx[pb0 + 3] : -1;
            if (k0 >= 0) sB[k0 * SROW + h] = acc[0];
            if (k1 >= 0) sB[k1 * SROW + h] = acc[1];
            if (k2 >= 0) sB[k2 * SROW + h] = acc[2];
            if (k3 >= 0) sB[k3 * SROW + h] = acc[3];
        }
    };

    // ---- pipeline: 2 tiles in flight; QK^T (compacted) as latency cover ----
    float4 x0, x1, x2, x3, x4, x5, x6, x7;
    float4 y0, y1, y2, y3, y4, y5, y6, y7;
    LOADC(wvid,     x0, x1, x2, x3, x4, x5, x6, x7);
    LOADC(wvid + 4, y0, y1, y2, y3, y4, y5, y6, y7);

    // QK^T over compacted positions (p = tid>>3 + 32i), + be, * 1/sqrt(16)
    {
        const int ha = lane & 7;
        const int pp = tid >> 3;
        const float beh = be[ha];
        const float4* qp = (const float4*)(Q + (size_t)bq * HIDDEN + ha * HDIM);
        const float4 q0 = qp[0], q1 = qp[1], q2 = qp[2], q3 = qp[3];
        #pragma unroll 2
        for (int i = 0; i < 16; i++) {
            const int p = pp + 32 * i;
            if (p < cnt) {
                const int k = sIdx[p];
                const float4* kp = (const float4*)(K + (size_t)(b * NSEQ + k) * HIDDEN + ha * HDIM);
                const float4 k0 = kp[0], k1 = kp[1], k2 = kp[2], k3 = kp[3];
                float p0 = q0.x * k0.x; p0 = fmaf(q0.y, k0.y, p0);
                p0 = fmaf(q0.z, k0.z, p0); p0 = fmaf(q0.w, k0.w, p0);
                float p1 = q1.x * k1.x; p1 = fmaf(q1.y, k1.y, p1);
                p1 = fmaf(q1.z, k1.z, p1); p1 = fmaf(q1.w, k1.w, p1);
                float p2 = q2.x * k2.x; p2 = fmaf(q2.y, k2.y, p2);
                p2 = fmaf(q2.z, k2.z, p2); p2 = fmaf(q2.w, k2.w, p2);
                float p3 = q3.x * k3.x; p3 = fmaf(q3.y, k3.y, p3);
                p3 = fmaf(q3.z, k3.z, p3); p3 = fmaf(q3.w, k3.w, p3);
                sS[k * SROW + ha] = fmaf((p0 + p1) + (p2 + p3), 0.25f, beh);
            }
        }
    }

    // steady rotation: {COMP(t); LOAD(t+8)} alternating X/Y, wave stride 4
    {
        bool useX = true;
        for (int tc = wvid; tc < ntiles; tc += 4) {
            if (useX) {
                COMPC(tc, x0, x1, x2, x3, x4, x5, x6, x7);
                if (tc + 8 < ntiles) LOADC(tc + 8, x0, x1, x2, x3, x4, x5, x6, x7);
            } else {
                COMPC(tc, y0, y1, y2, y3, y4, y5, y6, y7);
                if (tc + 8 < ntiles) LOADC(tc + 8, y0, y1, y2, y3, y4, y5, y6, y7);
            }
            useX = !useX;
        }
    }
    __syncthreads();   // the ONE barrier before softmax

    // ---- softmax per head over compacted positions (3-pass, no reg arrays) --
    {
        const int hh = tid >> 5;
        const int j0 = tid & 31;
        float m = NEGINF;
        for (int j = j0; j < cnt; j += 32) {
            const int k = sIdx[j];
            m = fmaxf(m, sS[k * SROW + hh] + sB[k * SROW + hh]);
        }
        #pragma unroll
        for (int off = 16; off >= 1; off >>= 1) m = fmaxf(m, __shfl_xor(m, off, 64));
        float sum = 0.f;
        for (int j = j0; j < cnt; j += 32) {
            const int k = sIdx[j];
            const float e = __expf(sS[k * SROW + hh] + sB[k * SROW + hh] - m);
            sS[k * SROW + hh] = e;
            sum += e;
        }
        #pragma unroll
        for (int off = 16; off >= 1; off >>= 1) sum += __shfl_xor(sum, off, 64);
        const float rinv = (sum > 0.f) ? 1.f / sum : 0.f;
        for (int j = j0; j < cnt; j += 32) {
            const int k = sIdx[j];
            sS[k * SROW + hh] *= rinv;
        }
    }
    __syncthreads();

    // ---- PV over compacted positions (sB reused as partials) ----
    float* sPd = sB;
    {
        const int d4 = tid & 31;            // d = 4*d4
        const int kg = tid >> 5;            // position stride 8
        const int hh = d4 >> 2;
        const float4* v4 = (const float4*)(V + (size_t)b * NSEQ * HIDDEN) + d4;
        float4 acc = make_float4(0.f, 0.f, 0.f, 0.f);
        for (int j = kg; j < cnt; j += 8) {
            const int k = sIdx[j];
            const float wgt = sS[k * SROW + hh];
            const float4 vv = v4[(size_t)k * 32];
            acc.x = fmaf(wgt, vv.x, acc.x);
            acc.y = fmaf(wgt, vv.y, acc.y);
            acc.z = fmaf(wgt, vv.z, acc.z);
            acc.w = fmaf(wgt, vv.w, acc.w);
        }
        *(float4*)(&sPd[kg * 132 + d4 * 4]) = acc;
    }
    __syncthreads();
    if (tid < HIDDEN) {
        float s = 0.f;
        #pragma unroll
        for (int gg = 0; gg < 8; gg++) s += sPd[gg * 132 + tid];
        attn[bq * HIDDEN + tid] = s;
    }
}

// ---------------- Kernel 3: output projection ----------------
__global__ __launch_bounds__(128) void out_proj(
    const float* __restrict__ attn,
    const float* __restrict__ Wo, const float* __restrict__ bo,
    float* __restrict__ out)
{
    const int ROWS = 8;
    __shared__ float sX[ROWS][HIDDEN];
    const int row0 = blockIdx.x * ROWS;
    const int tid = threadIdx.x;

    const float4* src = (const float4*)(attn + row0 * HIDDEN);
    float4* dst = (float4*)(&sX[0][0]);
    #pragma unroll
    for (int i = 0; i < ROWS * HIDDEN / 4 / 128; i++)
        dst[tid + i * 128] = src[tid + i * 128];
    __syncthreads();

    float acc[ROWS];
    #pragma unroll
    for (int r = 0; r < ROWS; r++) acc[r] = 0.f;
    const int c = tid;
    #pragma unroll 8
    for (int d = 0; d < HIDDEN; d++) {
        const float w = Wo[d * HIDDEN + c];
        #pragma unroll
        for (int r = 0; r < ROWS; r++)
            acc[r] = fmaf(sX[r][d], w, acc[r]);
    }
    const float bov = bo[c];
    #pragma unroll
    for (int r = 0; r < ROWS; r++)
        out[(row0 + r) * HIDDEN + c] = acc[r] + bov;
}

extern "C" void kernel_launch(void* const* d_in, const int* in_sizes, int n_in,
                              void* d_out, int out_size, void* d_ws, size_t ws_size,
                              hipStream_t stream) {
    const float* node = (const float*)d_in[0];
    const float* ef   = (const float*)d_in[1];
    const int*   mask = (const int*)d_in[2];
    const float* Wq = (const float*)d_in[3];
    const float* bq = (const float*)d_in[4];
    const float* Wk = (const float*)d_in[5];
    const float* bk = (const float*)d_in[6];
    const float* Wv = (const float*)d_in[7];
    const float* bv = (const float*)d_in[8];
    const float* We = (const float*)d_in[9];
    const float* be = (const float*)d_in[10];
    const float* Wo = (const float*)d_in[11];
    const float* bo = (const float*)d_in[12];
    float* out = (float*)d_out;

    const int ROWS_TOT = NBATCH * NSEQ;              // 2048
    const int RC = ROWS_TOT * HIDDEN;                // 262144 floats
    float* Q = (float*)d_ws;
    float* K = Q + RC;
    float* V = K + RC;
    float* attnb = V + RC;

    qkv_proj<<<ROWS_TOT / 8, 128, 0, stream>>>(node, Wq, bq, Wk, bk, Wv, bv, Q, K, V);
    attn_fused<<<ROWS_TOT, 256, 0, stream>>>(ef, mask, We, be, Q, K, V, attnb);
    out_proj<<<ROWS_TOT / 8, 128, 0, stream>>>(attnb, Wo, bo, out);
}